// Round 5
// baseline (149.358 us; speedup 1.0000x reference)
//
#include <hip/hip_runtime.h>
#include <stdint.h>

#define EMBED 768
#define NH 12
#define HD 64
#define Bsz 8
#define Ssz 1024
#define LOG2E 1.44269504088896f

typedef __attribute__((ext_vector_type(4))) float f32x4;
typedef __attribute__((ext_vector_type(16))) float f32x16;
typedef __attribute__((ext_vector_type(8))) _Float16 f16x8;
typedef __attribute__((ext_vector_type(4))) _Float16 f16x4;
typedef __attribute__((ext_vector_type(2))) _Float16 f16x2;
typedef __attribute__((ext_vector_type(4))) unsigned int u32x4;
typedef __attribute__((ext_vector_type(2))) unsigned int u32x2;

// ---------------------------------------------------------------------------
// Kernel 1: per-head QKV projection, transposed compute (Out^T = W^T x^T).
//   Q,K -> fp16 [B,H,S,64] (Q pre-scaled by log2 e) ; V -> fp16 [B,H,64,S]
// Block: 256 thr (4 waves), one (b,h) x 128 s-rows. All W staged once.
// NOTE: the LDS staging preamble before the first global store is empirically
// REQUIRED for post-timing stability (R6 post-mortem: a fast direct-store qkv
// diverged after timing, consistent with the harness's d_ws re-poison
// overlapping the replayed graph's first writes). DO NOT shave it.
// ---------------------------------------------------------------------------
__launch_bounds__(256)
__global__ void qkv_proj(const float* __restrict__ x,
                         const float* __restrict__ Wq, const float* __restrict__ bq,
                         const float* __restrict__ Wk, const float* __restrict__ bk,
                         const float* __restrict__ Wv, const float* __restrict__ bv,
                         _Float16* __restrict__ Qb, _Float16* __restrict__ Kb,
                         _Float16* __restrict__ Vt)
{
    __shared__ _Float16 XT[128 * 72];     // X tile [s][d] pad 72; later aliased as epilogue stage
    __shared__ _Float16 Wt[3 * 64 * 72];  // W^T [m][e][d] pad 72
    __shared__ float Bs[192];

    const int bt = blockIdx.x;
    const int st = bt & 7;
    const int h  = (bt >> 3) % NH;
    const int b  = bt / (8 * NH);
    const int sbase = st * 128;
    const int tid = threadIdx.x;
    const int lane = tid & 63, w = tid >> 6;
    const int l15 = lane & 15, quad = lane >> 4;

    // stage X tile (coalesced float4 reads of this head's 64-col slice)
    for (int i = 0; i < 8; ++i) {
        int idx = tid + 256 * i;          // 0..2047
        int row = idx >> 4;               // 0..127
        int c4  = (idx & 15) * 4;
        const float4 g = *(const float4*)&x[(size_t)(b * Ssz + sbase + row) * EMBED + h * HD + c4];
        f16x4 v; v[0] = (_Float16)g.x; v[1] = (_Float16)g.y; v[2] = (_Float16)g.z; v[3] = (_Float16)g.w;
        *(f16x4*)&XT[row * 72 + c4] = v;
    }
    // stage all three W^T (fp16): Wt[m][e][d] = W[d][e]
    {
        const float* Ws0[3] = {Wq, Wk, Wv};
        const float* bs0[3] = {bq, bk, bv};
#pragma unroll
        for (int m = 0; m < 3; ++m) {
            const float* W = Ws0[m] + (size_t)h * HD * HD;
            for (int i = 0; i < 4; ++i) {
                int idx = tid + 256 * i;  // 0..1023
                int d = idx >> 4, e4 = (idx & 15) * 4;
                float4 g = *(const float4*)&W[d * 64 + e4];
                Wt[m * 4608 + (e4 + 0) * 72 + d] = (_Float16)g.x;
                Wt[m * 4608 + (e4 + 1) * 72 + d] = (_Float16)g.y;
                Wt[m * 4608 + (e4 + 2) * 72 + d] = (_Float16)g.z;
                Wt[m * 4608 + (e4 + 3) * 72 + d] = (_Float16)g.w;
            }
        }
        if (tid < 192) Bs[tid] = bs0[tid >> 6][h * HD + (tid & 63)];
    }
    __syncthreads();

    // B-frags from XT: B[k=d][n=s]
    f16x8 bx[2][2];
    const int nbg0 = w * 2;               // this wave's two 16-row s-blocks
#pragma unroll
    for (int nb = 0; nb < 2; ++nb)
#pragma unroll
        for (int kh = 0; kh < 2; ++kh)
            bx[nb][kh] = *(const f16x8*)&XT[((nbg0 + nb) * 16 + l15) * 72 + kh * 32 + quad * 8];
    __syncthreads();                      // everyone done reading XT; reuse as stage

    const size_t qkbase = (size_t)(b * NH + h) * Ssz + sbase;
    const f32x4 zero = {0.f, 0.f, 0.f, 0.f};

#pragma unroll
    for (int m = 0; m < 3; ++m) {
        f32x4 acc[2][4];
#pragma unroll
        for (int nb = 0; nb < 2; ++nb)
#pragma unroll
            for (int eb = 0; eb < 4; ++eb) acc[nb][eb] = zero;
#pragma unroll
        for (int eb = 0; eb < 4; ++eb)
#pragma unroll
            for (int kh = 0; kh < 2; ++kh) {
                f16x8 aw = *(const f16x8*)&Wt[m * 4608 + (eb * 16 + l15) * 72 + kh * 32 + quad * 8];
#pragma unroll
                for (int nb = 0; nb < 2; ++nb)
                    acc[nb][eb] = __builtin_amdgcn_mfma_f32_16x16x32_f16(aw, bx[nb][kh], acc[nb][eb], 0, 0, 0);
            }

        if (m < 2) {
            // Q/K: stage [s][e] (f16x4 of 4 consecutive e), then coalesced f16x8 store
            const float sc = (m == 0) ? LOG2E : 1.0f;
#pragma unroll
            for (int nb = 0; nb < 2; ++nb)
#pragma unroll
                for (int eb = 0; eb < 4; ++eb) {
                    f32x4 bb = *(const f32x4*)&Bs[m * 64 + eb * 16 + quad * 4];
                    f16x4 v;
#pragma unroll
                    for (int r = 0; r < 4; ++r) v[r] = (_Float16)((acc[nb][eb][r] + bb[r]) * sc);
                    *(f16x4*)&XT[((nbg0 + nb) * 16 + l15) * 72 + eb * 16 + quad * 4] = v;
                }
            __syncthreads();
            _Float16* outp = (m == 0) ? Qb : Kb;
            for (int i = 0; i < 4; ++i) {
                int idx = tid + 256 * i;  // 0..1023
                int s = idx >> 3, e8 = (idx & 7) * 8;
                *(f16x8*)&outp[(qkbase + s) * HD + e8] = *(const f16x8*)&XT[s * 72 + e8];
            }
            __syncthreads();
        } else {
            // V: stage [e][s] pad 136, then coalesced V^T store
            _Float16* Vs = XT;            // [64][136] = 8704 el <= 9216
#pragma unroll
            for (int nb = 0; nb < 2; ++nb)
#pragma unroll
                for (int eb = 0; eb < 4; ++eb) {
                    f32x4 bb = *(const f32x4*)&Bs[128 + eb * 16 + quad * 4];
#pragma unroll
                    for (int r = 0; r < 4; ++r)
                        Vs[(eb * 16 + quad * 4 + r) * 136 + (nbg0 + nb) * 16 + l15] =
                            (_Float16)(acc[nb][eb][r] + bb[r]);
                }
            __syncthreads();
            for (int i = 0; i < 4; ++i) {
                int idx = tid + 256 * i;  // 0..1023
                int e = idx >> 4, s8 = (idx & 15) * 8;
                *(f16x8*)&Vt[((size_t)(b * NH + h) * 64 + e) * Ssz + sbase + s8] =
                    *(const f16x8*)&Vs[e * 136 + s8];
            }
        }
    }
}

// ---------------------------------------------------------------------------
// Kernel 2 (R13 = R12 softmax/PV machinery, 2-wave blocks):
// R12 post-mortem: passed at 46.4us but MfmaUtil 21 / VALUBusy 50 / Occ 21.6
// with grid=768 = 3 blocks/CU ceiling -- per-CU iteration period ~2300cy vs
// ~560cy of pipe work: latency/lockstep-bound, not pipe-bound. R13 halves the
// block to 2 waves x 32 q (64 q-rows), grid 768 -> 1536: LDS cap now 5
// blocks/CU (10 waves) and decorrelated block phases let one block's MFMA
// overlap another's softmax VALU. Per-wave work and total LDS-read traffic
// unchanged; staging DMA + K/V HBM demand double (L2-absorbed; all 16
// q-tiles of a head stay on one XCD via bt%96 -> bt%8 swizzle).
// Also: tile-max reduction restructured as a tree (depth ~5 vs 31).
// Cross-lane rules kept from R12: max via __shfl_xor (NEVER equal-operand
// permlane32_swap); denominator lane-local, one shfl after the loop; P-frag
// via 8 DISTINCT-operand permlane32_swap (T12). LDS 32KB. Block 128.
// ---------------------------------------------------------------------------
#define KVB 8192   /* elements per buffer: K 64x64 (4096) + V^T 64x64 (4096) */
__launch_bounds__(128)
__global__ void attn(const _Float16* __restrict__ Qb, const _Float16* __restrict__ Kb,
                     const _Float16* __restrict__ Vt, float* __restrict__ out)
{
    __shared__ _Float16 KV[2 * KVB];      // [buf][ K 64x64 | V^T 64x64 ], swizzled

    // XCD-locality: all 16 q-tiles of one head share (blockIdx % 8) -> same XCD
    const int bt = blockIdx.x;
    const int hh = bt % 96;               // b*NH + h
    const int qt = bt / 96;               // 0..15
    const int h  = hh % NH;
    const int b  = hh / NH;

    const int tid  = threadIdx.x;
    const int lane = tid & 63, w = tid >> 6;   // w = 0,1
    const int l31  = lane & 31;           // q within wave tile / A-frag row
    const int hf   = lane >> 5;           // k-half selector

    const size_t bh = (size_t)(b * NH + h);
    const _Float16* Qg = Qb + bh * Ssz * HD;
    const _Float16* Kg = Kb + bh * Ssz * HD;
    const _Float16* Vg = Vt + bh * (size_t)HD * Ssz;

    // Q B-frags: B[k=d][n=q]: n = l31, k = kk*16 + 8*hf + j
    const int qrow = qt * 64 + w * 32 + l31;
    f16x8 aq[4];
#pragma unroll
    for (int kk = 0; kk < 4; ++kk)
        aq[kk] = *(const f16x8*)&Qg[(size_t)qrow * HD + kk * 16 + hf * 8];

    // staging: 512 chunks of 16B per matrix per tile; 4 chunks/thread (128 thr).
    // global_load_lds writes LINEARLY (wave base + lane*16), so the read-side
    // XOR swizzle is realized by pre-swizzling the global source column:
    // stored granule g at row r must contain logical granule g ^ (r&7).
    // chunk c = tid + 128*i -> row r = r0 + 16*i (r0 = tid>>3), granule
    // g = (c&7)^(r&7) = (tid&7)^(r0&7) = g0 (constant across i: 16*i = 0 mod 8).
    const int r0 = tid >> 3;
    const int g0 = (tid & 7) ^ (r0 & 7);
    const _Float16* Kst = Kg + r0 * HD + g0 * 8;
    const _Float16* Vst = Vg + (size_t)r0 * Ssz + g0 * 8;

#define STAGE(buf, kt_) do {                                                                 \
    _Pragma("unroll")                                                                        \
    for (int i_ = 0; i_ < 4; ++i_) {                                                         \
        __builtin_amdgcn_global_load_lds(                                                    \
            (const __attribute__((address_space(1))) void*)(Kst + ((kt_) * 64 + i_ * 16) * HD), \
            (__attribute__((address_space(3))) void*)&KV[(buf) * KVB + (tid + 128 * i_) * 8],   \
            16, 0, 0);                                                                       \
        __builtin_amdgcn_global_load_lds(                                                    \
            (const __attribute__((address_space(1))) void*)(Vst + (size_t)i_ * 16 * Ssz + (kt_) * 64), \
            (__attribute__((address_space(3))) void*)&KV[(buf) * KVB + 4096 + (tid + 128 * i_) * 8],   \
            16, 0, 0);                                                                       \
    }                                                                                        \
} while (0)

    STAGE(0, 0);

    f32x16 o0, o1;                        // O^T e-blocks 0..31 / 32..63 (col = q)
#pragma unroll
    for (int i = 0; i < 16; ++i) { o0[i] = 0.f; o1[i] = 0.f; }
    float m_run = -INFINITY, l_run = 0.f; // l_run: THIS lane's t-subset only

    const int rsw = l31 * 64;             // A-frag row base in LDS (elements)
    const int sx  = (l31 & 7) << 3;       // swizzle term (row&7; rows r and r+32 agree)
    const int ch  = hf * 8;               // k-half column offset

    __asm__ __volatile__("s_waitcnt vmcnt(0)" ::: "memory");
    __syncthreads();

    for (int kt = 0; kt < 16; ++kt) {
        const int cur = kt & 1;
        if (kt < 15) STAGE(cur ^ 1, kt + 1);   // next tile DMA in flight all iter

        const _Float16* Ksb = &KV[cur * KVB];
        const _Float16* Vsb = &KV[cur * KVB + 4096];

        // S^T = K Q^T : lane holds col q=l31, rows t=(reg&3)+8*(reg>>2)+4*hf (+32 for st1)
        f32x16 st0, st1;
#pragma unroll
        for (int i = 0; i < 16; ++i) { st0[i] = 0.f; st1[i] = 0.f; }
        __builtin_amdgcn_s_setprio(1);
#pragma unroll
        for (int kk = 0; kk < 4; ++kk) {
            const int col = (kk * 16 + ch) ^ sx;
            f16x8 ak0 = *(const f16x8*)&Ksb[rsw + col];
            f16x8 ak1 = *(const f16x8*)&Ksb[2048 + rsw + col];
            st0 = __builtin_amdgcn_mfma_f32_32x32x16_f16(ak0, aq[kk], st0, 0, 0, 0);
            st1 = __builtin_amdgcn_mfma_f32_32x32x16_f16(ak1, aq[kk], st1, 0, 0, 0);
        }
        __builtin_amdgcn_s_setprio(0);

        // tile max: lane-local TREE over 32 regs (depth ~5), then cross-half
        // shuffle (proven primitive; never equal-operand permlane).
        float m8[8];
#pragma unroll
        for (int i = 0; i < 8; ++i)
            m8[i] = fmaxf(fmaxf(st0[i], st0[i + 8]), fmaxf(st1[i], st1[i + 8]));
        float m4a = fmaxf(m8[0], m8[4]), m4b = fmaxf(m8[1], m8[5]);
        float m4c = fmaxf(m8[2], m8[6]), m4d = fmaxf(m8[3], m8[7]);
        float mt = fmaxf(fmaxf(m4a, m4b), fmaxf(m4c, m4d));
        mt = fmaxf(mt, __shfl_xor(mt, 32, 64));

        // defer-max (T13): rescale only when tile max grows past THR=8 (log2 units,
        // Q pre-scaled by log2e). P then bounded by 2^8=256, fine in f16/f32 accum.
        if (__any(mt > m_run + 8.f)) {
            float mn = fmaxf(m_run, mt);
            float al = __builtin_amdgcn_exp2f(m_run - mn);
            m_run = mn;
            l_run *= al;
#pragma unroll
            for (int i = 0; i < 16; ++i) { o0[i] *= al; o1[i] *= al; }
        }

        // P = exp2(S - m_run), in place
#pragma unroll
        for (int i = 0; i < 16; ++i) st0[i] = __builtin_amdgcn_exp2f(st0[i] - m_run);
#pragma unroll
        for (int i = 0; i < 16; ++i) st1[i] = __builtin_amdgcn_exp2f(st1[i] - m_run);

        // denominator: lane-local f32 tree sum over OWN 32 t-values; the
        // cross-half combine happens ONCE after the loop (m_run is identical
        // in both half-lanes, so per-tile partial sums stay consistent).
        float a0 = 0.f, a1 = 0.f, a2 = 0.f, a3 = 0.f;
#pragma unroll
        for (int i = 0; i < 16; i += 4) {
            a0 += st0[i]; a1 += st0[i+1]; a2 += st0[i+2]; a3 += st0[i+3];
            a0 += st1[i]; a1 += st1[i+1]; a2 += st1[i+2]; a3 += st1[i+3];
        }
        l_run += (a0 + a1) + (a2 + a3);

        // O^T += V^T P^T. P^T B-frag (T12, one-swap-fills-two-dwords), operands
        // DISTINCT (X0!=Y0 etc.), mapping == R10's verified shfl+cndmask:
        //   swap(X0,Y0) -> (d0, d2) ; swap(X1,Y1) -> (d1, d3)
        // where X0=pk(c,c+1), X1=pk(c+2,c+3), Y0=pk(c+4,c+5), Y1=pk(c+6,c+7),
        // c = 8*(kk&1), block = st0/st1 by kk>>1.
        __builtin_amdgcn_s_setprio(1);
#pragma unroll
        for (int kk = 0; kk < 4; ++kk) {
            const f32x16& pp = (kk < 2) ? st0 : st1;   // t-block = kk>>1
            const int c = 8 * (kk & 1);
            unsigned X0 = __builtin_bit_cast(unsigned, __builtin_amdgcn_cvt_pkrtz(pp[c+0], pp[c+1]));
            unsigned X1 = __builtin_bit_cast(unsigned, __builtin_amdgcn_cvt_pkrtz(pp[c+2], pp[c+3]));
            unsigned Y0 = __builtin_bit_cast(unsigned, __builtin_amdgcn_cvt_pkrtz(pp[c+4], pp[c+5]));
            unsigned Y1 = __builtin_bit_cast(unsigned, __builtin_amdgcn_cvt_pkrtz(pp[c+6], pp[c+7]));
            u32x2 r02 = __builtin_amdgcn_permlane32_swap(X0, Y0, 0, 0);
            u32x2 r13 = __builtin_amdgcn_permlane32_swap(X1, Y1, 0, 0);
            u32x4 du = {r02[0], r13[0], r02[1], r13[1]};
            f16x8 bp = __builtin_bit_cast(f16x8, du);
            const int col = (kk * 16 + ch) ^ sx;
            f16x8 av0 = *(const f16x8*)&Vsb[rsw + col];
            f16x8 av1 = *(const f16x8*)&Vsb[2048 + rsw + col];
            o0 = __builtin_amdgcn_mfma_f32_32x32x16_f16(av0, bp, o0, 0, 0, 0);
            o1 = __builtin_amdgcn_mfma_f32_32x32x16_f16(av1, bp, o1, 0, 0, 0);
        }
        __builtin_amdgcn_s_setprio(0);

        __asm__ __volatile__("s_waitcnt vmcnt(0)" ::: "memory");  // next tile landed
        __syncthreads();
    }

    // combine the two half-subset denominators (single cross-lane op, proven
    // primitive), then normalize. e = (r&3)+8*(r>>2)+4*hf (+32 for o1); q=qrow.
    l_run += __shfl_xor(l_run, 32, 64);
    const float inv = 1.f / l_run;
    float* op = &out[((size_t)b * Ssz + qrow) * EMBED + h * HD];
#pragma unroll
    for (int r1 = 0; r1 < 4; ++r1) {
        f32x4 v0, v1;
#pragma unroll
        for (int r0_ = 0; r0_ < 4; ++r0_) {
            v0[r0_] = o0[4 * r1 + r0_] * inv;
            v1[r0_] = o1[4 * r1 + r0_] * inv;
        }
        *(f32x4*)&op[r1 * 8 + hf * 4]      = v0;
        *(f32x4*)&op[32 + r1 * 8 + hf * 4] = v1;
    }
#undef STAGE
}

extern "C" void kernel_launch(void* const* d_in, const int* in_sizes, int n_in,
                              void* d_out, int out_size, void* d_ws, size_t ws_size,
                              hipStream_t stream) {
    const float* x  = (const float*)d_in[0];
    const float* Wq = (const float*)d_in[1];
    const float* bq = (const float*)d_in[2];
    const float* Wk = (const float*)d_in[3];
    const float* bk = (const float*)d_in[4];
    const float* Wv = (const float*)d_in[5];
    const float* bv = (const float*)d_in[6];

    _Float16* Qb = (_Float16*)d_ws;                        // fp16 [B,H,S,64], pre-scaled by log2e
    _Float16* Kb = Qb + (size_t)Bsz * NH * Ssz * HD;       // fp16 [B,H,S,64]
    _Float16* Vt = Kb + (size_t)Bsz * NH * Ssz * HD;       // fp16 [B,H,64,S]

    qkv_proj<<<dim3(Bsz * NH * 8), dim3(256), 0, stream>>>(x, Wq, bq, Wk, bk, Wv, bv, Qb, Kb, Vt);
    attn<<<dim3(Bsz * NH * 16), dim3(128), 0, stream>>>(Qb, Kb, Vt, (float*)d_out);
}

// Round 6
// 129.576 us; speedup vs baseline: 1.1527x; 1.1527x over previous
//
#include <hip/hip_runtime.h>
#include <stdint.h>

#define EMBED 768
#define NH 12
#define HD 64
#define Bsz 8
#define Ssz 1024
#define LOG2E 1.44269504088896f

typedef __attribute__((ext_vector_type(4))) float f32x4;
typedef __attribute__((ext_vector_type(16))) float f32x16;
typedef __attribute__((ext_vector_type(8))) _Float16 f16x8;
typedef __attribute__((ext_vector_type(4))) _Float16 f16x4;
typedef __attribute__((ext_vector_type(2))) _Float16 f16x2;
typedef __attribute__((ext_vector_type(4))) unsigned int u32x4;
typedef __attribute__((ext_vector_type(2))) unsigned int u32x2;

// ---------------------------------------------------------------------------
// Kernel 1: per-head QKV projection, transposed compute (Out^T = W^T x^T).
//   Q,K -> fp16 [B,H,S,64] (Q pre-scaled by log2 e) ; V -> fp16 [B,H,64,S]
// Block: 256 thr (4 waves), one (b,h) x 128 s-rows. All W staged once.
// NOTE: the LDS staging preamble before the first global store is empirically
// REQUIRED for post-timing stability (R6 post-mortem: a fast direct-store qkv
// diverged after timing, consistent with the harness's d_ws re-poison
// overlapping the replayed graph's first writes). DO NOT shave it.
// ---------------------------------------------------------------------------
__launch_bounds__(256)
__global__ void qkv_proj(const float* __restrict__ x,
                         const float* __restrict__ Wq, const float* __restrict__ bq,
                         const float* __restrict__ Wk, const float* __restrict__ bk,
                         const float* __restrict__ Wv, const float* __restrict__ bv,
                         _Float16* __restrict__ Qb, _Float16* __restrict__ Kb,
                         _Float16* __restrict__ Vt)
{
    __shared__ _Float16 XT[128 * 72];     // X tile [s][d] pad 72; later aliased as epilogue stage
    __shared__ _Float16 Wt[3 * 64 * 72];  // W^T [m][e][d] pad 72
    __shared__ float Bs[192];

    const int bt = blockIdx.x;
    const int st = bt & 7;
    const int h  = (bt >> 3) % NH;
    const int b  = bt / (8 * NH);
    const int sbase = st * 128;
    const int tid = threadIdx.x;
    const int lane = tid & 63, w = tid >> 6;
    const int l15 = lane & 15, quad = lane >> 4;

    // stage X tile (coalesced float4 reads of this head's 64-col slice)
    for (int i = 0; i < 8; ++i) {
        int idx = tid + 256 * i;          // 0..2047
        int row = idx >> 4;               // 0..127
        int c4  = (idx & 15) * 4;
        const float4 g = *(const float4*)&x[(size_t)(b * Ssz + sbase + row) * EMBED + h * HD + c4];
        f16x4 v; v[0] = (_Float16)g.x; v[1] = (_Float16)g.y; v[2] = (_Float16)g.z; v[3] = (_Float16)g.w;
        *(f16x4*)&XT[row * 72 + c4] = v;
    }
    // stage all three W^T (fp16): Wt[m][e][d] = W[d][e]
    {
        const float* Ws0[3] = {Wq, Wk, Wv};
        const float* bs0[3] = {bq, bk, bv};
#pragma unroll
        for (int m = 0; m < 3; ++m) {
            const float* W = Ws0[m] + (size_t)h * HD * HD;
            for (int i = 0; i < 4; ++i) {
                int idx = tid + 256 * i;  // 0..1023
                int d = idx >> 4, e4 = (idx & 15) * 4;
                float4 g = *(const float4*)&W[d * 64 + e4];
                Wt[m * 4608 + (e4 + 0) * 72 + d] = (_Float16)g.x;
                Wt[m * 4608 + (e4 + 1) * 72 + d] = (_Float16)g.y;
                Wt[m * 4608 + (e4 + 2) * 72 + d] = (_Float16)g.z;
                Wt[m * 4608 + (e4 + 3) * 72 + d] = (_Float16)g.w;
            }
        }
        if (tid < 192) Bs[tid] = bs0[tid >> 6][h * HD + (tid & 63)];
    }
    __syncthreads();

    // B-frags from XT: B[k=d][n=s]
    f16x8 bx[2][2];
    const int nbg0 = w * 2;               // this wave's two 16-row s-blocks
#pragma unroll
    for (int nb = 0; nb < 2; ++nb)
#pragma unroll
        for (int kh = 0; kh < 2; ++kh)
            bx[nb][kh] = *(const f16x8*)&XT[((nbg0 + nb) * 16 + l15) * 72 + kh * 32 + quad * 8];
    __syncthreads();                      // everyone done reading XT; reuse as stage

    const size_t qkbase = (size_t)(b * NH + h) * Ssz + sbase;
    const f32x4 zero = {0.f, 0.f, 0.f, 0.f};

#pragma unroll
    for (int m = 0; m < 3; ++m) {
        f32x4 acc[2][4];
#pragma unroll
        for (int nb = 0; nb < 2; ++nb)
#pragma unroll
            for (int eb = 0; eb < 4; ++eb) acc[nb][eb] = zero;
#pragma unroll
        for (int eb = 0; eb < 4; ++eb)
#pragma unroll
            for (int kh = 0; kh < 2; ++kh) {
                f16x8 aw = *(const f16x8*)&Wt[m * 4608 + (eb * 16 + l15) * 72 + kh * 32 + quad * 8];
#pragma unroll
                for (int nb = 0; nb < 2; ++nb)
                    acc[nb][eb] = __builtin_amdgcn_mfma_f32_16x16x32_f16(aw, bx[nb][kh], acc[nb][eb], 0, 0, 0);
            }

        if (m < 2) {
            // Q/K: stage [s][e] (f16x4 of 4 consecutive e), then coalesced f16x8 store
            const float sc = (m == 0) ? LOG2E : 1.0f;
#pragma unroll
            for (int nb = 0; nb < 2; ++nb)
#pragma unroll
                for (int eb = 0; eb < 4; ++eb) {
                    f32x4 bb = *(const f32x4*)&Bs[m * 64 + eb * 16 + quad * 4];
                    f16x4 v;
#pragma unroll
                    for (int r = 0; r < 4; ++r) v[r] = (_Float16)((acc[nb][eb][r] + bb[r]) * sc);
                    *(f16x4*)&XT[((nbg0 + nb) * 16 + l15) * 72 + eb * 16 + quad * 4] = v;
                }
            __syncthreads();
            _Float16* outp = (m == 0) ? Qb : Kb;
            for (int i = 0; i < 4; ++i) {
                int idx = tid + 256 * i;  // 0..1023
                int s = idx >> 3, e8 = (idx & 7) * 8;
                *(f16x8*)&outp[(qkbase + s) * HD + e8] = *(const f16x8*)&XT[s * 72 + e8];
            }
            __syncthreads();
        } else {
            // V: stage [e][s] pad 136, then coalesced V^T store
            _Float16* Vs = XT;            // [64][136] = 8704 el <= 9216
#pragma unroll
            for (int nb = 0; nb < 2; ++nb)
#pragma unroll
                for (int eb = 0; eb < 4; ++eb) {
                    f32x4 bb = *(const f32x4*)&Bs[128 + eb * 16 + quad * 4];
#pragma unroll
                    for (int r = 0; r < 4; ++r)
                        Vs[(eb * 16 + quad * 4 + r) * 136 + (nbg0 + nb) * 16 + l15] =
                            (_Float16)(acc[nb][eb][r] + bb[r]);
                }
            __syncthreads();
            for (int i = 0; i < 4; ++i) {
                int idx = tid + 256 * i;  // 0..1023
                int e = idx >> 4, s8 = (idx & 15) * 8;
                *(f16x8*)&Vt[((size_t)(b * NH + h) * 64 + e) * Ssz + sbase + s8] =
                    *(const f16x8*)&Vs[e * 136 + s8];
            }
        }
    }
}

// ---------------------------------------------------------------------------
// Kernel 2 (R14 = R12 machinery + QK/softmax double-pipeline):
// R13 lesson: resident blocks/CU ~= 2 regardless of block size/LDS -> waves/CU
// scales with BLOCK size; smaller blocks = less parallelism (65us, occ 13.7%).
// Reverted to R12's 768 x 256-thr shape (best: 46.4us).
// R12's limiter: serial chain QK -> softmax -> PV (~1000cy/iter) with MFMA 21%/
// VALU 50% -- neither pipe near full. R14 overlaps QK(t+1) (MFMA pipe) with
// softmax(t) (VALU pipe): S(t+1) has no consumer until iter t+1, so the two
// phases are independent. K/V triple-buffered (stage(t+2) must not overwrite
// V(t) mid-PV under 2 buffers). Loop fully unrolled: both S states (sA/sB)
// and all %3 buffer indices are compile-time (rule #20). LDS 48KB.
// Cross-lane rules from R12 kept verbatim: max via __shfl_xor; denominator
// lane-local + one shfl post-loop; P-frag via DISTINCT-operand
// permlane32_swap (T12); NEVER equal-operand permlane32_swap.
// ---------------------------------------------------------------------------
#define KVB 8192   /* elements per buffer: K 64x64 (4096) + V^T 64x64 (4096) */
__launch_bounds__(256, 2)
__global__ void attn(const _Float16* __restrict__ Qb, const _Float16* __restrict__ Kb,
                     const _Float16* __restrict__ Vt, float* __restrict__ out)
{
    __shared__ _Float16 KV[3 * KVB];      // [buf0|buf1|buf2][ K 64x64 | V^T 64x64 ], swizzled

    // XCD-locality: all 8 q-tiles of one head share (blockIdx % 8) -> same XCD
    const int bt = blockIdx.x;
    const int hh = bt % 96;               // b*NH + h
    const int qt = bt / 96;
    const int h  = hh % NH;
    const int b  = hh / NH;

    const int tid  = threadIdx.x;
    const int lane = tid & 63, w = tid >> 6;
    const int l31  = lane & 31;           // q within wave tile / A-frag row
    const int hf   = lane >> 5;           // k-half selector

    const size_t bh = (size_t)(b * NH + h);
    const _Float16* Qg = Qb + bh * Ssz * HD;
    const _Float16* Kg = Kb + bh * Ssz * HD;
    const _Float16* Vg = Vt + bh * (size_t)HD * Ssz;

    // Q B-frags: B[k=d][n=q]: n = l31, k = kk*16 + 8*hf + j
    const int qrow = qt * 128 + w * 32 + l31;
    f16x8 aq[4];
#pragma unroll
    for (int kk = 0; kk < 4; ++kk)
        aq[kk] = *(const f16x8*)&Qg[(size_t)qrow * HD + kk * 16 + hf * 8];

    // staging: 512 chunks of 16B per matrix per tile; 2 chunks/thread.
    // global_load_lds writes LINEARLY (wave base + lane*16), so the read-side
    // XOR swizzle is realized by pre-swizzling the global source column:
    // stored granule g at row r must contain logical granule g ^ (r&7).
    const int ca = tid, cb = tid + 256;
    const int ra = ca >> 3, ga = (ca & 7) ^ (ra & 7);
    const int rb = cb >> 3, gb = (cb & 7) ^ (rb & 7);
    const _Float16* Ka  = Kg + ra * HD + ga * 8;
    const _Float16* Kb2 = Kg + rb * HD + gb * 8;
    const _Float16* Va  = Vg + (size_t)ra * Ssz + ga * 8;
    const _Float16* Vb  = Vg + (size_t)rb * Ssz + gb * 8;

#define STAGE(buf, kt_) do {                                                            \
    __builtin_amdgcn_global_load_lds(                                                   \
        (const __attribute__((address_space(1))) void*)(Ka + (kt_) * 64 * HD),          \
        (__attribute__((address_space(3))) void*)&KV[(buf) * KVB + ca * 8], 16, 0, 0);  \
    __builtin_amdgcn_global_load_lds(                                                   \
        (const __attribute__((address_space(1))) void*)(Kb2 + (kt_) * 64 * HD),         \
        (__attribute__((address_space(3))) void*)&KV[(buf) * KVB + cb * 8], 16, 0, 0);  \
    __builtin_amdgcn_global_load_lds(                                                   \
        (const __attribute__((address_space(1))) void*)(Va + (kt_) * 64),               \
        (__attribute__((address_space(3))) void*)&KV[(buf) * KVB + 4096 + ca * 8], 16, 0, 0); \
    __builtin_amdgcn_global_load_lds(                                                   \
        (const __attribute__((address_space(1))) void*)(Vb + (kt_) * 64),               \
        (__attribute__((address_space(3))) void*)&KV[(buf) * KVB + 4096 + cb * 8], 16, 0, 0); \
} while (0)

    const int rsw = l31 * 64;             // A-frag row base in LDS (elements)
    const int sx  = (l31 & 7) << 3;       // swizzle term (row&7; rows r and r+32 agree)
    const int ch  = hf * 8;               // k-half column offset

// S^T = K Q^T for one 64-t tile from buffer bufi; results into d0 (t 0..31),
// d1 (t 32..63). Lane holds col q=l31, rows t=(reg&3)+8*(reg>>2)+4*hf (+32).
#define QKT(d0, d1, bufi) do {                                                   \
    const _Float16* Ksb_ = &KV[(bufi) * KVB];                                    \
    _Pragma("unroll")                                                            \
    for (int i_ = 0; i_ < 16; ++i_) { d0[i_] = 0.f; d1[i_] = 0.f; }              \
    __builtin_amdgcn_s_setprio(1);                                               \
    _Pragma("unroll")                                                            \
    for (int kk_ = 0; kk_ < 4; ++kk_) {                                          \
        const int col_ = (kk_ * 16 + ch) ^ sx;                                   \
        f16x8 ak0_ = *(const f16x8*)&Ksb_[rsw + col_];                           \
        f16x8 ak1_ = *(const f16x8*)&Ksb_[2048 + rsw + col_];                    \
        d0 = __builtin_amdgcn_mfma_f32_32x32x16_f16(ak0_, aq[kk_], d0, 0, 0, 0); \
        d1 = __builtin_amdgcn_mfma_f32_32x32x16_f16(ak1_, aq[kk_], d1, 0, 0, 0); \
    }                                                                            \
    __builtin_amdgcn_s_setprio(0);                                               \
} while (0)

    STAGE(0, 0);

    f32x16 o0, o1;                        // O^T e-blocks 0..31 / 32..63 (col = q)
#pragma unroll
    for (int i = 0; i < 16; ++i) { o0[i] = 0.f; o1[i] = 0.f; }
    float m_run = -INFINITY, l_run = 0.f; // l_run: THIS lane's t-subset only

    __asm__ __volatile__("s_waitcnt vmcnt(0)" ::: "memory");
    __syncthreads();                       // buf0 ready

    STAGE(1, 1);                           // buf1 DMA in flight under QK(0)
    f32x16 sA0, sA1, sB0, sB1;             // two S states (tile kt in sA if kt even)
    QKT(sA0, sA1, 0);

    __asm__ __volatile__("s_waitcnt vmcnt(0)" ::: "memory");
    __syncthreads();                       // buf1 ready

#pragma unroll
    for (int kt = 0; kt < 16; ++kt) {
        const int bc = kt % 3;             // buffer holding tile kt
        const int bn = (kt + 1) % 3;       // buffer holding tile kt+1 (ready)
        const int bs = (kt + 2) % 3;       // buffer to stage tile kt+2 into

        if (kt < 14) STAGE(bs, kt + 2);    // DMA in flight across this iter

        // QK(t+1) on the MFMA pipe -- overlaps the softmax VALU below.
        if (kt < 15) {
            if (kt & 1) QKT(sA0, sA1, bn);
            else        QKT(sB0, sB1, bn);
        }

        f32x16& c0 = (kt & 1) ? sB0 : sA0; // current tile's scores (static select)
        f32x16& c1 = (kt & 1) ? sB1 : sA1;

        // tile max: lane-local tree over 32 regs + cross-half shuffle
        float m8[8];
#pragma unroll
        for (int i = 0; i < 8; ++i)
            m8[i] = fmaxf(fmaxf(c0[i], c0[i + 8]), fmaxf(c1[i], c1[i + 8]));
        float m4a = fmaxf(m8[0], m8[4]), m4b = fmaxf(m8[1], m8[5]);
        float m4c = fmaxf(m8[2], m8[6]), m4d = fmaxf(m8[3], m8[7]);
        float mt = fmaxf(fmaxf(m4a, m4b), fmaxf(m4c, m4d));
        mt = fmaxf(mt, __shfl_xor(mt, 32, 64));

        // defer-max (T13): rescale only when tile max grows past THR=8 (log2 units)
        if (__any(mt > m_run + 8.f)) {
            float mn = fmaxf(m_run, mt);
            float al = __builtin_amdgcn_exp2f(m_run - mn);
            m_run = mn;
            l_run *= al;
#pragma unroll
            for (int i = 0; i < 16; ++i) { o0[i] *= al; o1[i] *= al; }
        }

        // P = exp2(S - m_run), in place
#pragma unroll
        for (int i = 0; i < 16; ++i) c0[i] = __builtin_amdgcn_exp2f(c0[i] - m_run);
#pragma unroll
        for (int i = 0; i < 16; ++i) c1[i] = __builtin_amdgcn_exp2f(c1[i] - m_run);

        // denominator: lane-local f32 tree sum over OWN 32 t-values; cross-half
        // combine happens ONCE after the loop (m_run identical across half-pair).
        float a0 = 0.f, a1 = 0.f, a2 = 0.f, a3 = 0.f;
#pragma unroll
        for (int i = 0; i < 16; i += 4) {
            a0 += c0[i]; a1 += c0[i+1]; a2 += c0[i+2]; a3 += c0[i+3];
            a0 += c1[i]; a1 += c1[i+1]; a2 += c1[i+2]; a3 += c1[i+3];
        }
        l_run += (a0 + a1) + (a2 + a3);

        // O^T += V^T P^T. P^T B-frag (T12, one-swap-fills-two-dwords), operands
        // DISTINCT: swap(X0,Y0) -> (d0w, d2w); swap(X1,Y1) -> (d1w, d3w), where
        // X0=pk(c,c+1), X1=pk(c+2,c+3), Y0=pk(c+4,c+5), Y1=pk(c+6,c+7), c=8*(kk&1).
        const _Float16* Vsb = &KV[bc * KVB + 4096];
        __builtin_amdgcn_s_setprio(1);
#pragma unroll
        for (int kk = 0; kk < 4; ++kk) {
            const f32x16& pp = (kk < 2) ? c0 : c1;   // t-block = kk>>1
            const int c = 8 * (kk & 1);
            unsigned X0 = __builtin_bit_cast(unsigned, __builtin_amdgcn_cvt_pkrtz(pp[c+0], pp[c+1]));
            unsigned X1 = __builtin_bit_cast(unsigned, __builtin_amdgcn_cvt_pkrtz(pp[c+2], pp[c+3]));
            unsigned Y0 = __builtin_bit_cast(unsigned, __builtin_amdgcn_cvt_pkrtz(pp[c+4], pp[c+5]));
            unsigned Y1 = __builtin_bit_cast(unsigned, __builtin_amdgcn_cvt_pkrtz(pp[c+6], pp[c+7]));
            u32x2 r02 = __builtin_amdgcn_permlane32_swap(X0, Y0, 0, 0);
            u32x2 r13 = __builtin_amdgcn_permlane32_swap(X1, Y1, 0, 0);
            u32x4 du = {r02[0], r13[0], r02[1], r13[1]};
            f16x8 bp = __builtin_bit_cast(f16x8, du);
            const int col = (kk * 16 + ch) ^ sx;
            f16x8 av0 = *(const f16x8*)&Vsb[rsw + col];
            f16x8 av1 = *(const f16x8*)&Vsb[2048 + rsw + col];
            o0 = __builtin_amdgcn_mfma_f32_32x32x16_f16(av0, bp, o0, 0, 0, 0);
            o1 = __builtin_amdgcn_mfma_f32_32x32x16_f16(av1, bp, o1, 0, 0, 0);
        }
        __builtin_amdgcn_s_setprio(0);

        if (kt < 15) {
            __asm__ __volatile__("s_waitcnt vmcnt(0)" ::: "memory");  // stage(kt+2) landed
            __syncthreads();
        }
    }

    // combine the two half-subset denominators (single cross-lane op), then
    // normalize. e = (r&3)+8*(r>>2)+4*hf (+32 for o1); q = qrow.
    l_run += __shfl_xor(l_run, 32, 64);
    const float inv = 1.f / l_run;
    float* op = &out[((size_t)b * Ssz + qrow) * EMBED + h * HD];
#pragma unroll
    for (int r1 = 0; r1 < 4; ++r1) {
        f32x4 v0, v1;
#pragma unroll
        for (int r0 = 0; r0 < 4; ++r0) {
            v0[r0] = o0[4 * r1 + r0] * inv;
            v1[r0] = o1[4 * r1 + r0] * inv;
        }
        *(f32x4*)&op[r1 * 8 + hf * 4]      = v0;
        *(f32x4*)&op[32 + r1 * 8 + hf * 4] = v1;
    }
#undef STAGE
#undef QKT
}

extern "C" void kernel_launch(void* const* d_in, const int* in_sizes, int n_in,
                              void* d_out, int out_size, void* d_ws, size_t ws_size,
                              hipStream_t stream) {
    const float* x  = (const float*)d_in[0];
    const float* Wq = (const float*)d_in[1];
    const float* bq = (const float*)d_in[2];
    const float* Wk = (const float*)d_in[3];
    const float* bk = (const float*)d_in[4];
    const float* Wv = (const float*)d_in[5];
    const float* bv = (const float*)d_in[6];

    _Float16* Qb = (_Float16*)d_ws;                        // fp16 [B,H,S,64], pre-scaled by log2e
    _Float16* Kb = Qb + (size_t)Bsz * NH * Ssz * HD;       // fp16 [B,H,S,64]
    _Float16* Vt = Kb + (size_t)Bsz * NH * Ssz * HD;       // fp16 [B,H,64,S]

    qkv_proj<<<dim3(Bsz * NH * 8), dim3(256), 0, stream>>>(x, Wq, bq, Wk, bk, Wv, bv, Qb, Kb, Vt);
    attn<<<dim3(Bsz * NH * 8), dim3(256), 0, stream>>>(Qb, Kb, Vt, (float*)d_out);
}